// Round 3
// 3234.106 us; speedup vs baseline: 1.1169x; 1.1169x over previous
//
#include <hip/hip_runtime.h>
#include <stdint.h>

// ---------------------------------------------------------------------------
// Encoder_Processor round 7: tensor-parallel pipeline, latency-optimized.
// 7 levels x 8 shards (56 WGs x 512 thr), weights in registers. All global
// exchange is MFMA-frag-linear f16, moved with 16B sc0/sc1 asm ops.
// R7 = R6 + register-hazard fixes (rule #18, root cause of R6's absmax 0.249):
//  - phase-B poll: BOTH flag loads + s_waitcnt fused into ONE asm ("=&v"
//    early-clobber) -- compares now data-depend on an asm that contains the
//    waitcnt, so they can never read the VGPR before the load retires.
//    (Separate load-asm / wait-asm / compare was IR-hoistable: pure icmp has
//    no memory side effect and could slide between load and waitcnt.)
//  - phase-G gate inputs pmv/phh: laundered via no-op asm volatile "+v"
//    AFTER the shared vwait -- volatile asms are mutually ordered, so every
//    consumer depends on a post-waitcnt definition. (All other batched-load
//    consumers are LDS stores, which the "memory" clobber already orders --
//    that is why R4 was safe.)
// R5 changes vs R4 (all latency-path, no numerics change):
//  - flag publishes: raw vwait+sc0sc1 store instead of __hip_atomic_store
//    RELEASE/AGENT (kills the legalizer's buffer_wbl2 L2-writeback sweep,
//    2x per step on the critical path)
//  - flags spread to one 128B line each; gentle s_sleep backoff in polls
//  - xt[t+1] prefetch, zg reads and nmR/hvR gate reads all ride phase-G's
//    G1-gather round trip (one vwait); zg distributed via LDS zL[256]
// ---------------------------------------------------------------------------

typedef _Float16 f16x8 __attribute__((ext_vector_type(8)));
typedef float    f32x4 __attribute__((ext_vector_type(4)));

static constexpr int SS = 256, BB = 64, DIN = 256, DH = 256, DNN = 512, DA = 64;
static constexpr int FS = 32;   // u32 stride between flags = 128B (own line)

// workspace layout (bytes)
static constexpr size_t OFF_FLAGS = 0;                     // u32[4096] = 16KB
static constexpr size_t OFF_WEMB  = 16384;
static constexpr size_t SZ_WEMB   = (size_t)DIN * DH * 2;
static constexpr size_t OFF_W     = OFF_WEMB + SZ_WEMB;
static constexpr size_t SZ_WU     = (size_t)DH * DNN * 2;
static constexpr size_t OFF_U     = OFF_W + SZ_WU;
static constexpr size_t OFF_W1    = OFF_U + SZ_WU;
static constexpr size_t SZ_W1     = (size_t)DNN * DH * 2;
static constexpr size_t OFF_WA1   = OFF_W1 + SZ_W1;
static constexpr size_t SZ_WA     = (size_t)DH * DA * 2;
static constexpr size_t OFF_UA1   = OFF_WA1 + SZ_WA;
static constexpr size_t OFF_NM    = OFF_UA1 + SZ_WA;       // 8 x 64KB fp32 [t][s]
static constexpr size_t SZ_NM     = (size_t)SS * BB * 4;
static constexpr size_t OFF_HV    = OFF_NM + 8 * SZ_NM;
static constexpr size_t OFF_G1    = OFF_HV + 8 * SZ_NM;    // 8 x 64KB f16 frag
static constexpr size_t SZ_G1     = (size_t)BB * DNN * 2;
static constexpr size_t OFF_Z     = OFF_G1 + 8 * SZ_G1;    // 8 x 4KB fp32
static constexpr size_t OFF_HB    = (size_t)4 << 20;       // 8 x 8MB f16 frag [t][kq<32][s<64]
static constexpr size_t SZ_HB     = (size_t)SS * BB * DH * 2;
static constexpr size_t WS_NEEDED = OFF_HB + 8 * SZ_HB;

__device__ __forceinline__ float lrelu(float v) { return v >= 0.0f ? v : 0.01f * v; }

// --- 16B / 4B coherent (L1+L2 bypass, L3 coherence point) asm ops ----------
// Loads: value NOT valid until vwait()! Callers batch issues then vwait once.
// RULE: after vwait, only MEMORY-op consumers (LDS/global stores) are safe.
// Any pure-register consumer must be laundered (asm volatile "+v") first.
__device__ __forceinline__ f32x4 ld128(const f32x4* p) {
  f32x4 r;
  asm volatile("global_load_dwordx4 %0, %1, off sc0 sc1" : "=v"(r) : "v"(p) : "memory");
  return r;
}
__device__ __forceinline__ void st128(f32x4* p, f32x4 v) {
  asm volatile("global_store_dwordx4 %0, %1, off sc0 sc1" :: "v"(p), "v"(v) : "memory");
}
__device__ __forceinline__ float ldf(const float* p) {
  float r;
  asm volatile("global_load_dword %0, %1, off sc0 sc1" : "=v"(r) : "v"(p) : "memory");
  return r;
}
__device__ __forceinline__ void stf(float* p, float v) {
  asm volatile("global_store_dword %0, %1, off sc0 sc1" :: "v"(p), "v"(v) : "memory");
}
__device__ __forceinline__ void stu(unsigned* p, unsigned v) {
  asm volatile("global_store_dword %0, %1, off sc0 sc1" :: "v"(p), "v"(v) : "memory");
}
__device__ __forceinline__ void vwait() {
  asm volatile("s_waitcnt vmcnt(0)" ::: "memory");
  __builtin_amdgcn_sched_barrier(0);
}

// poll one flag (all lanes, same addr -> one request/iter); load+wait fused
// in ONE asm so the compare data-depends on a post-waitcnt definition.
__device__ __forceinline__ void pollf(const unsigned* p, unsigned need) {
  #pragma nounroll
  for (int g = 0; g < (1 << 18); ++g) {
    unsigned v;
    asm volatile("global_load_dword %0, %1, off sc0 sc1\n\ts_waitcnt vmcnt(0)"
                 : "=v"(v) : "v"(p) : "memory");
    if (v >= need) return;
    if (g > 64)     __builtin_amdgcn_s_sleep(2);
    else if (g > 8) __builtin_amdgcn_s_sleep(1);
  }
}

// ---------------------------------------------------------------------------
__global__ void zero_flags_k(unsigned* f) {
  #pragma unroll
  for (int i = 0; i < 4; ++i) f[threadIdx.x + 1024 * i] = 0u;
}

// pack fp32 row-major [K][N] into f16 MFMA B-frag order
__global__ void pack_weight_k(const float* __restrict__ src, _Float16* __restrict__ dst,
                              int K, int N) {
  int idx = blockIdx.x * 256 + threadIdx.x;
  if (idx >= K * N) return;
  int k = idx / N, n = idx - k * N;
  int kt = k >> 5, q = (k >> 3) & 3, jj = k & 7;
  int nt = n >> 4, l = n & 15;
  size_t p = (((size_t)(kt * (N >> 4) + nt) * 4 + q) * 16 + l) * 8 + jj;
  dst[p] = (_Float16)src[idx];
}

// ---------------------------------------------------------------------------
// embedding: xe = x@W_emb + b_emb -> level-0 h buffer in FRAG layout
// ---------------------------------------------------------------------------
__global__ __launch_bounds__(512, 2) void emb_k(const float* __restrict__ xin,
                                                const float* __restrict__ b_emb,
                                                char* __restrict__ ws) {
  const int tid = threadIdx.x, wave = tid >> 6, lane = tid & 63;
  const int l15 = lane & 15, quad = lane >> 4;
  const _Float16* Wp = (const _Float16*)(ws + OFF_WEMB);
  _Float16* xe = (_Float16*)(ws + OFF_HB);

  f16x8 bE[16];
  #pragma unroll
  for (int kt = 0; kt < 8; ++kt)
    #pragma unroll
    for (int i = 0; i < 2; ++i)
      bE[kt * 2 + i] = *(const f16x8*)(Wp + (((size_t)(kt * 16 + (wave * 2 + i)) * 4 + quad) * 16 + l15) * 8);
  float ber[2] = { b_emb[(wave * 2) * 16 + l15], b_emb[(wave * 2 + 1) * 16 + l15] };

  __shared__ __align__(16) _Float16 xtF[32 * 65 * 8];
  __shared__ __align__(16) _Float16 oF[32 * 65 * 8];

  for (int tt = 0; tt < 4; ++tt) {
    const int t = (int)blockIdx.x + 64 * tt;
    #pragma unroll
    for (int c = 0; c < 4; ++c) {
      int u = tid + 512 * c, s = u >> 5, kg = u & 31;
      const float* src = xin + ((size_t)s * SS + t) * DIN + kg * 8;
      f32x4 v0 = *(const f32x4*)src, v1 = *(const f32x4*)(src + 4);
      f16x8 p;
      p[0]=(_Float16)v0[0]; p[1]=(_Float16)v0[1]; p[2]=(_Float16)v0[2]; p[3]=(_Float16)v0[3];
      p[4]=(_Float16)v1[0]; p[5]=(_Float16)v1[1]; p[6]=(_Float16)v1[2]; p[7]=(_Float16)v1[3];
      *(f16x8*)(xtF + ((size_t)kg * 65 + s) * 8) = p;
    }
    __syncthreads();
    f32x4 acc[2][4] = {};
    #pragma unroll
    for (int kt = 0; kt < 8; ++kt) {
      f16x8 ax[4];
      #pragma unroll
      for (int mt = 0; mt < 4; ++mt)
        ax[mt] = *(const f16x8*)(xtF + (((size_t)(kt * 4 + quad)) * 65 + (mt * 16 + l15)) * 8);
      #pragma unroll
      for (int i = 0; i < 2; ++i)
        #pragma unroll
        for (int mt = 0; mt < 4; ++mt)
          acc[i][mt] = __builtin_amdgcn_mfma_f32_16x16x32_f16(ax[mt], bE[kt * 2 + i], acc[i][mt], 0, 0, 0);
    }
    #pragma unroll
    for (int i = 0; i < 2; ++i) {
      int n = (wave * 2 + i) * 16 + l15;
      int kq = n >> 3, jn = n & 7;
      #pragma unroll
      for (int mt = 0; mt < 4; ++mt)
        #pragma unroll
        for (int r = 0; r < 4; ++r) {
          int s = mt * 16 + quad * 4 + r;
          oF[((size_t)kq * 65 + s) * 8 + jn] = (_Float16)(acc[i][mt][r] + ber[i]);
        }
    }
    __syncthreads();
    #pragma unroll
    for (int c = 0; c < 4; ++c) {
      int u = tid + 512 * c, kq = u >> 6, s = u & 63;
      f32x4 v = *(const f32x4*)(oF + ((size_t)kq * 65 + s) * 8);
      *((f32x4*)(xe + (((size_t)t * 32 + kq) * 64 + s) * 8)) = v;  // plain; kernel-end flush
    }
    __syncthreads();
  }
}

// ---------------------------------------------------------------------------
// pipeline: 56 WGs (7 levels x 8 shards) x 512 thr, 1 WG/CU
// ---------------------------------------------------------------------------
__global__ __launch_bounds__(512, 2) void pipe_k(
    const float* __restrict__ mask, const float* __restrict__ b_in,
    const float* __restrict__ b1v, const float* __restrict__ bA1,
    const float* __restrict__ WA3, const float* __restrict__ bA3,
    char* __restrict__ ws, float* __restrict__ outp) {
  const int level = 1 + ((int)blockIdx.x >> 3);
  const int j     = (int)blockIdx.x & 7;
  const int tid   = threadIdx.x, wave = tid >> 6, lane = tid & 63;
  const int l15   = lane & 15, quad = lane >> 4;

  unsigned* flags = (unsigned*)(ws + OFF_FLAGS);
  unsigned* hfl   = flags + (size_t)level * 8 * FS;         // own-level h flags
  unsigned* hflP  = flags + (size_t)(level - 1) * 8 * FS;   // prev-level h flags
  unsigned* gfl   = flags + (size_t)(8 + level) * 8 * FS;   // own-level G1 flags

  const _Float16* Wp   = (const _Float16*)(ws + OFF_W);
  const _Float16* Up   = (const _Float16*)(ws + OFF_U);
  const _Float16* W1p  = (const _Float16*)(ws + OFF_W1);
  const _Float16* WA1p = (const _Float16*)(ws + OFF_WA1);
  const _Float16* UA1p = (const _Float16*)(ws + OFF_UA1);

  const f32x4* hPrev4 = (const f32x4*)((_Float16*)(ws + OFF_HB) + (size_t)(level - 1) * SS * BB * DH);
  f32x4*       hOwn4  = (f32x4*)((_Float16*)(ws + OFF_HB) + (size_t)level * SS * BB * DH);
  f32x4*       g1g4   = (f32x4*)(ws + OFF_G1 + (size_t)level * SZ_G1);
  float*       zg     = (float*)(ws + OFF_Z + (size_t)level * 4096);
  float*       nmW    = (float*)(ws + OFF_NM + (size_t)level * SZ_NM);
  float*       hvW    = (float*)(ws + OFF_HV + (size_t)level * SZ_NM);
  const float* nmR    = (const float*)(ws + OFF_NM + (size_t)(level - 1) * SZ_NM);
  const float* hvR    = (const float*)(ws + OFF_HV + (size_t)(level - 1) * SZ_NM);

  // --- weight chunks in registers ---
  const int ntG = j * 4 + (wave >> 1);   // W/U n-tile (of 32)
  const int m0  = (wave & 1) * 2;        // G1 m-tile pair
  f16x8 bW[8], bU[8];
  #pragma unroll
  for (int kt = 0; kt < 8; ++kt) {
    bW[kt] = *(const f16x8*)(Wp + (((size_t)(kt * 32 + ntG) * 4 + quad) * 16 + l15) * 8);
    bU[kt] = *(const f16x8*)(Up + (((size_t)(kt * 32 + ntG) * 4 + quad) * 16 + l15) * 8);
  }
  const int nt1 = j * 2 + (wave & 1);    // W1 n-tile (of 16)
  const int mt1 = wave >> 1;             // combine m-tile
  f16x8 b1f[16];
  #pragma unroll
  for (int kt = 0; kt < 16; ++kt)
    b1f[kt] = *(const f16x8*)(W1p + (((size_t)(kt * 16 + nt1) * 4 + quad) * 16 + l15) * 8);

  const int nG = ntG * 16 + l15;
  const int nC = nt1 * 16 + l15;
  const float bir  = b_in[nG];
  const float b1r  = b1v[nC];
  const float wa3r = WA3[(j & 3) * 16 + l15];
  const float ba1r = bA1[(j & 3) * 16 + l15];
  const float bA3v = bA3[0];

  // --- LDS (~146 KB) ---
  __shared__ __align__(16) _Float16 xtF[32 * 64 * 8];   // 32 KB  xt[t] frags
  __shared__ __align__(16) _Float16 htF[32 * 64 * 8];   // 32 KB  h[t-1] frags
  __shared__ __align__(16) _Float16 g1F[64 * 64 * 8];   // 64 KB  G1 frags
  __shared__ __align__(16) _Float16 waF[16 * 64 * 8];   // 16 KB  action b-frags
  __shared__ float gB[64], gX[64], gH[64], gHv[64];
  __shared__ float zL[256];                             // action z staging

  if (j < 4) {
    for (int u = tid; u < 1024; u += 512) {
      int ktm = u >> 6, lu = u & 63, kt = ktm >> 1, m = ktm & 1;
      const _Float16* sp = (m ? UA1p : WA1p) +
          (((size_t)(kt * 4 + j) * 4 + (lu >> 4)) * 16 + (lu & 15)) * 8;
      *(f16x8*)(waF + (size_t)u * 8) = *(const f16x8*)sp;
    }
  }
  for (int i = tid; i < 32 * 64 * 8; i += 512) htF[i] = (_Float16)0;
  if (tid < 64) gHv[tid] = 0.0f;
  float hreg[4] = {0.f, 0.f, 0.f, 0.f};
  __syncthreads();

  // prologue: stage xt[0]
  if (level >= 2) pollf(hflP + wave * FS, 1);
  __syncthreads();
  {
    f32x4 pf0[4];
    #pragma unroll
    for (int c = 0; c < 4; ++c) pf0[c] = ld128(hPrev4 + tid + 512 * c);
    vwait();
    #pragma unroll
    for (int c = 0; c < 4; ++c) ((f32x4*)xtF)[tid + 512 * c] = pf0[c];
  }
  __syncthreads();

  for (int t = 0; t < SS; ++t) {
    const bool last = (t == SS - 1);

    // -- B: fused producer polls (own h peers >= t AND prev level >= t+2).
    //    Both loads + waitcnt in ONE asm: compares data-depend on outputs
    //    of the asm containing the waitcnt (no hoist hazard). Early-clobber
    //    "=&v" so v1's dest can't alias p2's address pair.
    {
      const unsigned need1 = (unsigned)t;   // t==0 -> always satisfied
      const unsigned need2 = (level >= 2)
          ? (unsigned)((t + 2 <= SS) ? (t + 2) : SS) : 0u;
      const unsigned* p1 = hfl + wave * FS;
      const unsigned* p2 = (level >= 2) ? (hflP + wave * FS) : p1;
      #pragma nounroll
      for (int g = 0; g < (1 << 18); ++g) {
        unsigned v1, v2;
        asm volatile("global_load_dword %0, %2, off sc0 sc1\n\t"
                     "global_load_dword %1, %3, off sc0 sc1\n\t"
                     "s_waitcnt vmcnt(0)"
                     : "=&v"(v1), "=&v"(v2) : "v"(p1), "v"(p2) : "memory");
        if (v1 >= need1 && v2 >= need2) break;
        if (g > 64)     __builtin_amdgcn_s_sleep(2);
        else if (g > 8) __builtin_amdgcn_s_sleep(1);
      }
    }

    // -- C: gather h[t-1] peer chunk (wave w <- shard w) --
    if (t > 0 && wave != j) {
      const f32x4* src = hOwn4 + (size_t)(t - 1) * 2048 + wave * 256;
      f32x4 hv4[4];
      #pragma unroll
      for (int it = 0; it < 4; ++it) hv4[it] = ld128(src + it * 64 + lane);
      vwait();
      #pragma unroll
      for (int it = 0; it < 4; ++it) ((f32x4*)htF)[wave * 256 + it * 64 + lane] = hv4[it];
    }
    __syncthreads();

    // -- D: G1 = lrelu(xt@W + h@U + b) own chunk; action partials --
    {
      f32x4 a0 = {}, a1 = {};
      #pragma unroll
      for (int kt = 0; kt < 8; ++kt) {
        int kq = kt * 4 + quad;
        f16x8 ax0 = *(const f16x8*)(xtF + ((size_t)(kq * 64 + m0 * 16 + l15)) * 8);
        f16x8 ax1 = *(const f16x8*)(xtF + ((size_t)(kq * 64 + (m0 + 1) * 16 + l15)) * 8);
        f16x8 ah0 = *(const f16x8*)(htF + ((size_t)(kq * 64 + m0 * 16 + l15)) * 8);
        f16x8 ah1 = *(const f16x8*)(htF + ((size_t)(kq * 64 + (m0 + 1) * 16 + l15)) * 8);
        a0 = __builtin_amdgcn_mfma_f32_16x16x32_f16(ax0, bW[kt], a0, 0, 0, 0);
        a1 = __builtin_amdgcn_mfma_f32_16x16x32_f16(ax1, bW[kt], a1, 0, 0, 0);
        a0 = __builtin_amdgcn_mfma_f32_16x16x32_f16(ah0, bU[kt], a0, 0, 0, 0);
        a1 = __builtin_amdgcn_mfma_f32_16x16x32_f16(ah1, bU[kt], a1, 0, 0, 0);
      }
      const int kqn = nG >> 3, jn = nG & 7;
      #pragma unroll
      for (int r = 0; r < 4; ++r) {
        g1F[((size_t)kqn * 64 + (m0 * 16 + quad * 4 + r)) * 8 + jn]       = (_Float16)lrelu(a0[r] + bir);
        g1F[((size_t)kqn * 64 + ((m0 + 1) * 16 + quad * 4 + r)) * 8 + jn] = (_Float16)lrelu(a1[r] + bir);
      }
      if (j < 4 && wave < 4) {  // action shard: cols [j*16, j*16+16), m-tile = wave
        f32x4 aa = {};
        #pragma unroll
        for (int kt = 0; kt < 8; ++kt) {
          int kq = kt * 4 + quad;
          f16x8 ax = *(const f16x8*)(xtF + ((size_t)(kq * 64 + wave * 16 + l15)) * 8);
          f16x8 ah = *(const f16x8*)(htF + ((size_t)(kq * 64 + wave * 16 + l15)) * 8);
          f16x8 bWa = *(const f16x8*)(waF + ((size_t)(kt * 2) * 64 + lane) * 8);
          f16x8 bUa = *(const f16x8*)(waF + ((size_t)(kt * 2 + 1) * 64 + lane) * 8);
          aa = __builtin_amdgcn_mfma_f32_16x16x32_f16(ax, bWa, aa, 0, 0, 0);
          aa = __builtin_amdgcn_mfma_f32_16x16x32_f16(ah, bUa, aa, 0, 0, 0);
        }
        #pragma unroll
        for (int r = 0; r < 4; ++r) {
          float v = lrelu(aa[r] + ba1r) * wa3r;
          v += __shfl_xor(v, 1); v += __shfl_xor(v, 2);
          v += __shfl_xor(v, 4); v += __shfl_xor(v, 8);
          if (l15 == 0) stf(&zg[j * 64 + wave * 16 + quad * 4 + r], v);
        }
      }
    }
    __syncthreads();
    // publish own G1 chunk (16B, frag-linear); flag via raw store (no wbl2)
    {
      f32x4 v = ((const f32x4*)g1F)[j * 512 + tid];
      st128(g1g4 + j * 512 + tid, v);
      vwait();
    }
    __syncthreads();
    if (tid == 0) stu(gfl + j * FS, (unsigned)(t + 1));

    // -- G: poll peers' G1; gather G1 + zg + xt[t+1] + gate inputs, 1 vwait --
    f32x4 pf[4];
    float pmv = 1.0f, phh = 0.0f;
    {
      float zv = 0.0f;
      const bool wantZ = (wave < 4);
      const bool wantGate = (tid < 64) && (level >= 2);
      if (wave != j) {
        pollf(gfl + wave * FS, (unsigned)(t + 1));
        const f32x4* src = g1g4 + wave * 512;
        f32x4 g4[8];
        #pragma unroll
        for (int it = 0; it < 8; ++it) g4[it] = ld128(src + it * 64 + lane);
        if (wantZ) zv = ldf(zg + wave * 64 + lane);
        if (!last) {
          const f32x4* xs = hPrev4 + (size_t)(t + 1) * 2048;
          #pragma unroll
          for (int c = 0; c < 4; ++c) pf[c] = ld128(xs + tid + 512 * c);
        }
        if (wantGate) {
          size_t tn = (t + 1 < SS) ? (size_t)(t + 1) : 0;
          pmv = ldf(nmR + tn * BB + tid);
          phh = ldf(hvR + (size_t)t * BB + tid);
        }
        vwait();
        #pragma unroll
        for (int it = 0; it < 8; ++it) ((f32x4*)g1F)[wave * 512 + it * 64 + lane] = g4[it];
      } else {
        if (wantZ) zv = ldf(zg + wave * 64 + lane);
        if (!last) {
          const f32x4* xs = hPrev4 + (size_t)(t + 1) * 2048;
          #pragma unroll
          for (int c = 0; c < 4; ++c) pf[c] = ld128(xs + tid + 512 * c);
        }
        if (wantGate) {
          size_t tn = (t + 1 < SS) ? (size_t)(t + 1) : 0;
          pmv = ldf(nmR + tn * BB + tid);
          phh = ldf(hvR + (size_t)t * BB + tid);
        }
        vwait();
      }
      // launder pure-register consumers of asm-load outputs: pin their defs
      // AFTER the waitcnt (volatile asms are mutually ordered).
      if (wantGate) asm volatile("" : "+v"(pmv), "+v"(phh));
      if (wantZ) zL[wave * 64 + lane] = zv;
    }
    __syncthreads();

    // -- H: gates (wave 0, LDS/regs only) + W1 MFMA (all waves) --
    if (tid < 64) {
      const int s = tid;
      float pm, phv;
      if (level == 1) {
        float mv = mask[(size_t)s * SS + t];
        pm = mv; phv = mv;
      } else {
        pm  = (t + 1 < SS) ? pmv : 1.0f;
        phv = phh;
      }
      float z    = bA3v + zL[s] + zL[64 + s] + zL[128 + s] + zL[192 + s];
      float nm0  = fminf(fmaxf(0.2f * z + 0.5f, 0.0f), 1.0f);
      float lv   = last ? 1.0f : 0.0f;
      float nm   = (1.0f - lv) * (pm * phv * nm0);
      float hvp  = gHv[s], omn = 1.0f - nm;
      float both = pm * phv * omn * hvp;
      float xo   = pm * phv * (nm + omn * (1.0f - hvp));
      float ho   = (1.0f - pm * phv) * omn * hvp;
      float hv   = both + xo + ho;
      gB[s] = both; gX[s] = xo; gH[s] = ho; gHv[s] = hv;
      if (j == 0 && level < 7) {
        stf(&nmW[(size_t)t * BB + s], nm);
        stf(&hvW[(size_t)t * BB + s], hv);
      }
    }
    f32x4 c1 = {};
    #pragma unroll
    for (int kt = 0; kt < 16; ++kt) {
      f16x8 ag = *(const f16x8*)(g1F + ((size_t)((kt * 4 + quad) * 64 + mt1 * 16 + l15)) * 8);
      c1 = __builtin_amdgcn_mfma_f32_16x16x32_f16(ag, b1f[kt], c1, 0, 0, 0);
    }
    __syncthreads();

    // -- I: combine; publish own h chunk; rotate xt buffer --
    {
      const int kqc = nC >> 3, jc = nC & 7;
      #pragma unroll
      for (int r = 0; r < 4; ++r) {
        int s = mt1 * 16 + quad * 4 + r;
        float h1  = lrelu(c1[r] + b1r);
        float xtv = (float)xtF[((size_t)(kqc * 64 + s)) * 8 + jc];
        float hn  = gB[s] * h1 + gX[s] * xtv + gH[s] * hreg[r];
        hreg[r] = hn;
        htF[((size_t)(kqc * 64 + s)) * 8 + jc] = (_Float16)hn;
        if (level == 7 && last) outp[(size_t)s * DH + nC] = hn;
      }
    }
    __syncthreads();
    if (tid < 256) {
      f32x4 v = ((const f32x4*)htF)[j * 256 + tid];
      st128(hOwn4 + (size_t)t * 2048 + j * 256 + tid, v);
    }
    if (!last) {  // pf already materialized at G's vwait
      #pragma unroll
      for (int c = 0; c < 4; ++c) ((f32x4*)xtF)[tid + 512 * c] = pf[c];
    }
    vwait();
    __syncthreads();
    if (tid == 0) stu(hfl + j * FS, (unsigned)(t + 1));
  }
}

// ---------------------------------------------------------------------------
extern "C" void kernel_launch(void* const* d_in, const int* in_sizes, int n_in,
                              void* d_out, int out_size, void* d_ws, size_t ws_size,
                              hipStream_t stream) {
  const float* x     = (const float*)d_in[0];
  const float* mask  = (const float*)d_in[1];
  const float* W_emb = (const float*)d_in[3];
  const float* b_emb = (const float*)d_in[4];
  const float* W     = (const float*)d_in[5];
  const float* U     = (const float*)d_in[6];
  const float* b     = (const float*)d_in[7];
  const float* W1    = (const float*)d_in[8];
  const float* b1    = (const float*)d_in[9];
  const float* WA1   = (const float*)d_in[10];
  const float* UA1   = (const float*)d_in[11];
  const float* bA1   = (const float*)d_in[12];
  const float* WA3   = (const float*)d_in[13];
  const float* bA3   = (const float*)d_in[14];
  char* ws = (char*)d_ws;

  if (ws_size < WS_NEEDED) return;

  zero_flags_k<<<1, 1024, 0, stream>>>((unsigned*)(ws + OFF_FLAGS));
  pack_weight_k<<<(DIN * DH + 255) / 256, 256, 0, stream>>>(W_emb, (_Float16*)(ws + OFF_WEMB), DIN, DH);
  pack_weight_k<<<(DH * DNN + 255) / 256, 256, 0, stream>>>(W, (_Float16*)(ws + OFF_W), DH, DNN);
  pack_weight_k<<<(DH * DNN + 255) / 256, 256, 0, stream>>>(U, (_Float16*)(ws + OFF_U), DH, DNN);
  pack_weight_k<<<(DNN * DH + 255) / 256, 256, 0, stream>>>(W1, (_Float16*)(ws + OFF_W1), DNN, DH);
  pack_weight_k<<<(DH * DA + 255) / 256, 256, 0, stream>>>(WA1, (_Float16*)(ws + OFF_WA1), DH, DA);
  pack_weight_k<<<(DH * DA + 255) / 256, 256, 0, stream>>>(UA1, (_Float16*)(ws + OFF_UA1), DH, DA);

  emb_k<<<64, 512, 0, stream>>>(x, b_emb, ws);
  pipe_k<<<56, 512, 0, stream>>>(mask, b, b1, bA1, WA3, bA3, ws, (float*)d_out);
}